// Round 6
// baseline (133.989 us; speedup 1.0000x reference)
//
#include <hip/hip_runtime.h>

#define BB 32
#define NN_ 128
#define NIN 64
#define MH 256
#define MO 64
#define NH 256
#define NO 64
#define EDGES 16256

typedef __attribute__((ext_vector_type(8))) short short8;   // 8 bf16 = 4 VGPRs
typedef __attribute__((ext_vector_type(4))) float f32x4;    // MFMA acc
typedef __attribute__((ext_vector_type(2))) float f32x2;    // v_pk_* pair

// ws layout (floats):
//   psb: [B][32][128][8] bf16  off 0        = 524288 floats
//   prb: [B][N][256]     bf16  off 524288   = 524288 floats
//   w2b: [32][64][8]     bf16  off 1048576  = 8192 floats
//   agg: [B][N][MO]      fp32  off 1056768  = 262144 floats
//   o1b: [256][64]       bf16  off 1318912  = 8192 floats
//   o2b: [256][256]      bf16  off 1327104  = 32768 floats
//   o3b: [64][256]       bf16  off 1359872  = 8192 floats

static __device__ __forceinline__ unsigned short f2bf(float f) {  // RNE-ish
    unsigned u = __float_as_uint(f);
    u = (u + 0x7fffu + ((u >> 16) & 1u)) >> 16;
    return (unsigned short)u;
}

// pack two fp32 into packed bf16 (round-half-away; valid for any sign)
static __device__ __forceinline__ unsigned bf_pack(float lo, float hi) {
    return __builtin_amdgcn_perm(__float_as_uint(hi) + 0x8000u,
                                 __float_as_uint(lo) + 0x8000u, 0x07060302u);
}

static __device__ __forceinline__ short8 pack8(float4 f0, float4 f1) {
    uint4 u;
    u.x = bf_pack(f0.x, f0.y);
    u.y = bf_pack(f0.z, f0.w);
    u.z = bf_pack(f1.x, f1.y);
    u.w = bf_pack(f1.z, f1.w);
    return __builtin_bit_cast(short8, u);
}

// unpack uint4 (8 packed bf16) into 4 f32x2 pairs
static __device__ __forceinline__ void unpack8v(uint4 u, f32x2* f) {
    f[0] = (f32x2){__uint_as_float(u.x << 16), __uint_as_float(u.x & 0xffff0000u)};
    f[1] = (f32x2){__uint_as_float(u.y << 16), __uint_as_float(u.y & 0xffff0000u)};
    f[2] = (f32x2){__uint_as_float(u.z << 16), __uint_as_float(u.z & 0xffff0000u)};
    f[3] = (f32x2){__uint_as_float(u.w << 16), __uint_as_float(u.w & 0xffff0000u)};
}

// A-fragment build: relu(s+p) with v_pk_add_f32 / v_pk_max_f32, pack w/ round
static __device__ __forceinline__ short8 buildAv(const f32x2* s, const f32x2* p) {
    uint4 u;
    #pragma unroll
    for (int i = 0; i < 4; ++i) {
        f32x2 h = s[i] + p[i];                                   // v_pk_add_f32
        h = __builtin_elementwise_max(h, (f32x2){0.f, 0.f});     // v_pk_max_f32
        ((unsigned*)&u)[i] = bf_pack(h.x, h.y);
    }
    return __builtin_bit_cast(short8, u);
}

// ---------------------------------------------------------------------------
// Kernel 1: prep (unchanged from R5).
// ---------------------------------------------------------------------------
__global__ __launch_bounds__(256) void prep_kernel(
    const float* __restrict__ x, const float* __restrict__ W1,
    const float* __restrict__ b1, const float* __restrict__ W2,
    const float* __restrict__ O1, const float* __restrict__ O2,
    const float* __restrict__ O3,
    unsigned short* __restrict__ psb, unsigned short* __restrict__ prb,
    unsigned short* __restrict__ w2b, unsigned short* __restrict__ o1b,
    unsigned short* __restrict__ o2b, unsigned short* __restrict__ o3b)
{
    int blk = blockIdx.x;
    int t = threadIdx.x;
    if (blk < 256) {
        int row0 = blk << 4;
        int b = blk >> 3;
        int w = t >> 6, lane = t & 63, ml = lane & 15, q = lane >> 4;

        short8 aX[2];
        #pragma unroll
        for (int s = 0; s < 2; ++s) {
            const float* base = x + (size_t)(row0 + ml) * NIN + s * 32 + q * 8;
            aX[s] = pack8(*(const float4*)base, *(const float4*)(base + 4));
        }

        #pragma unroll
        for (int half = 0; half < 2; ++half) {
            #pragma unroll
            for (int nt = 0; nt < 4; ++nt) {
                int col = w * 64 + nt * 16 + ml;
                const float* wrow = W1 + (size_t)col * (2 * NIN) + half * 64 + q * 8;
                f32x4 acc = (f32x4){0.f, 0.f, 0.f, 0.f};
                #pragma unroll
                for (int s = 0; s < 2; ++s) {
                    short8 bw = pack8(*(const float4*)(wrow + 32 * s),
                                      *(const float4*)(wrow + 32 * s + 4));
                    acc = __builtin_amdgcn_mfma_f32_16x16x32_bf16(aX[s], bw, acc, 0, 0, 0);
                }
                if (half == 0) {
                    #pragma unroll
                    for (int reg = 0; reg < 4; ++reg) {
                        int n = (row0 + q * 4 + reg) & 127;
                        psb[((size_t)(b * 32 + (col >> 3)) * NN_ + n) * 8 + (col & 7)]
                            = f2bf(acc[reg]);
                    }
                } else {
                    float bv = b1[col];
                    #pragma unroll
                    for (int reg = 0; reg < 4; ++reg) {
                        int n = (row0 + q * 4 + reg) & 127;
                        prb[((size_t)(b * NN_) + n) * MH + col] = f2bf(acc[reg] + bv);
                    }
                }
            }
        }
    } else if (blk < 320) {
        int i = ((blk - 256) << 8) + t;
        int kc4 = i >> 9, rem = i & 511;
        int n = rem >> 3, k7 = i & 7;
        w2b[i] = f2bf(W2[n * MH + kc4 * 8 + k7]);
    } else {
        int i = ((blk - 320) << 8) + t;
        if (i < 16384)       o1b[i]         = f2bf(O1[i]);
        else if (i < 81920)  o2b[i - 16384] = f2bf(O2[i - 16384]);
        else                 o3b[i - 81920] = f2bf(O3[i - 81920]);
    }
}

// ---------------------------------------------------------------------------
// Kernel 2: edge fc2, bf16 MFMA, 2 receivers/block, dense sender mapping.
// R6: explicit register double-buffer on the 4 uint4 loads per k-step
// (prefetch kc+1 before consuming kc) + v_pk_add/max A-build.
// ---------------------------------------------------------------------------
__global__ __launch_bounds__(256, 3) void edge_kernel(
    const float* __restrict__ rt, const float* __restrict__ b2,
    const unsigned short* __restrict__ psb, const unsigned short* __restrict__ prb,
    const unsigned short* __restrict__ w2b, float* __restrict__ agg)
{
    int blk = blockIdx.x;
    int b = blk >> 6;
    int r0 = (blk & 63) << 1;
    int tid = threadIdx.x;
    int w = tid >> 6, lane = tid & 63, ml = lane & 15, q = lane >> 4;

    __shared__ float rtw_lds[2][128];
    __shared__ float red[2][4][64];
    {
        int rr = tid >> 7, s = tid & 127;
        int r = r0 + rr;
        float v = 0.f;
        if (s != r) {
            int e = r * 127 + s - (s > r ? 1 : 0);
            const float* p = rt + ((size_t)(b * EDGES + e)) * 2;
            v = p[0] + p[1];
        }
        rtw_lds[rr][s] = v;
    }
    __syncthreads();

    int slot0 = 32 * w + ml;
    int slot1 = slot0 + 16;

    const uint4* ps4 = (const uint4*)psb + (size_t)b * (32 * NN_);       // [kc4][node]
    const uint4* pr4_0 = (const uint4*)(prb + ((size_t)(b * NN_ + r0)) * MH);
    const uint4* pr4_1 = (const uint4*)(prb + ((size_t)(b * NN_ + r0 + 1)) * MH);
    const uint4* w24 = (const uint4*)w2b;                                // [kc4][n]

    f32x4 acc[2][2][4];   // [receiver][m-tile][n-tile]
    #pragma unroll
    for (int rr = 0; rr < 2; ++rr)
        #pragma unroll
        for (int mt = 0; mt < 2; ++mt)
            #pragma unroll
            for (int nt = 0; nt < 4; ++nt)
                acc[rr][mt][nt] = (f32x4){0.f, 0.f, 0.f, 0.f};

    // --- software pipeline: stage kc=0 ---
    uint4 us0 = ps4[q * NN_ + slot0];
    uint4 us1 = ps4[q * NN_ + slot1];
    uint4 up0 = pr4_0[q];
    uint4 up1 = pr4_1[q];
    uint4 uw0 = w24[q * 64 + ml];           // nt=0 weight prefetch

    #pragma unroll
    for (int kc = 0; kc < 8; ++kc) {
        int kc4 = 4 * kc + q;
        // prefetch next k-step while current compute runs
        uint4 nus0, nus1, nup0, nup1, nuw0;
        if (kc < 7) {
            int kn = kc4 + 4;
            nus0 = ps4[kn * NN_ + slot0];
            nus1 = ps4[kn * NN_ + slot1];
            nup0 = pr4_0[kn];
            nup1 = pr4_1[kn];
            nuw0 = w24[kn * 64 + ml];
        }

        f32x2 s0f[4], s1f[4], p0f[4], p1f[4];
        unpack8v(us0, s0f); unpack8v(us1, s1f);
        unpack8v(up0, p0f); unpack8v(up1, p1f);

        short8 a00 = buildAv(s0f, p0f);   // r0, m-tile 0
        short8 a01 = buildAv(s1f, p0f);   // r0, m-tile 1
        short8 a10 = buildAv(s0f, p1f);   // r1, m-tile 0
        short8 a11 = buildAv(s1f, p1f);   // r1, m-tile 1

        uint4 uwc = uw0;
        #pragma unroll
        for (int nt = 0; nt < 4; ++nt) {
            short8 bw = __builtin_bit_cast(short8, uwc);
            if (nt < 3) uwc = w24[kc4 * 64 + 16 * (nt + 1) + ml];
            acc[0][0][nt] = __builtin_amdgcn_mfma_f32_16x16x32_bf16(a00, bw, acc[0][0][nt], 0, 0, 0);
            acc[0][1][nt] = __builtin_amdgcn_mfma_f32_16x16x32_bf16(a01, bw, acc[0][1][nt], 0, 0, 0);
            acc[1][0][nt] = __builtin_amdgcn_mfma_f32_16x16x32_bf16(a10, bw, acc[1][0][nt], 0, 0, 0);
            acc[1][1][nt] = __builtin_amdgcn_mfma_f32_16x16x32_bf16(a11, bw, acc[1][1][nt], 0, 0, 0);
        }

        if (kc < 7) { us0 = nus0; us1 = nus1; up0 = nup0; up1 = nup1; uw0 = nuw0; }
    }

    float b2c[4];
    #pragma unroll
    for (int nt = 0; nt < 4; ++nt) b2c[nt] = b2[16 * nt + ml];

    #pragma unroll
    for (int rr = 0; rr < 2; ++rr) {
        float colsum[4] = {0.f, 0.f, 0.f, 0.f};
        #pragma unroll
        for (int mt = 0; mt < 2; ++mt) {
            int slotbase = 32 * w + 16 * mt + 4 * q;
            #pragma unroll
            for (int reg = 0; reg < 4; ++reg) {
                float rw = rtw_lds[rr][slotbase + reg];
                #pragma unroll
                for (int nt = 0; nt < 4; ++nt)
                    colsum[nt] += fmaxf(acc[rr][mt][nt][reg] + b2c[nt], 0.f) * rw;
            }
        }
        #pragma unroll
        for (int nt = 0; nt < 4; ++nt) {
            colsum[nt] += __shfl_xor(colsum[nt], 16);
            colsum[nt] += __shfl_xor(colsum[nt], 32);
        }
        if (lane < 16) {
            #pragma unroll
            for (int nt = 0; nt < 4; ++nt) red[rr][w][16 * nt + ml] = colsum[nt];
        }
    }
    __syncthreads();
    if (tid < 128) {
        int rr = tid >> 6, o = tid & 63;
        agg[((size_t)(b * NN_ + r0 + rr)) * MO + o] =
            red[rr][0][o] + red[rr][1][o] + red[rr][2][o] + red[rr][3][o];
    }
}

// ---------------------------------------------------------------------------
// Kernel 3: node MLP as 3 chained bf16 MFMAs (unchanged).
// ---------------------------------------------------------------------------
__global__ __launch_bounds__(256) void node_kernel(
    const float* __restrict__ agg,
    const unsigned short* __restrict__ O1b, const float* __restrict__ b1o,
    const unsigned short* __restrict__ O2b, const float* __restrict__ b2o,
    const unsigned short* __restrict__ O3b, const float* __restrict__ b3o,
    float* __restrict__ out)
{
    int tid = threadIdx.x;
    int w = tid >> 6, lane = tid & 63, ml = lane & 15, q = lane >> 4;
    int row0 = blockIdx.x << 4;

    __shared__ unsigned short h1L[16][264];
    __shared__ unsigned short h2L[16][264];

    short8 aA[2];
    #pragma unroll
    for (int s = 0; s < 2; ++s) {
        const float* base = agg + (size_t)(row0 + ml) * MO + 32 * s + q * 8;
        aA[s] = pack8(*(const float4*)base, *(const float4*)(base + 4));
    }

    #pragma unroll
    for (int nt = 0; nt < 4; ++nt) {
        int ntg = w * 4 + nt;
        f32x4 acc = (f32x4){0.f, 0.f, 0.f, 0.f};
        #pragma unroll
        for (int s = 0; s < 2; ++s) {
            uint4 uw = *(const uint4*)(O1b + (size_t)(ntg * 16 + ml) * 64 + 32 * s + q * 8);
            acc = __builtin_amdgcn_mfma_f32_16x16x32_bf16(
                aA[s], __builtin_bit_cast(short8, uw), acc, 0, 0, 0);
        }
        float bv = b1o[ntg * 16 + ml];
        #pragma unroll
        for (int reg = 0; reg < 4; ++reg)
            h1L[q * 4 + reg][ntg * 16 + ml] = f2bf(fmaxf(acc[reg] + bv, 0.f));
    }
    __syncthreads();

    short8 aH[8];
    #pragma unroll
    for (int ks = 0; ks < 8; ++ks)
        aH[ks] = *(const short8*)&h1L[ml][32 * ks + q * 8];
    #pragma unroll
    for (int nt = 0; nt < 4; ++nt) {
        int ntg = w * 4 + nt;
        const unsigned short* wrow = O2b + (size_t)(ntg * 16 + ml) * NH + q * 8;
        f32x4 acc = (f32x4){0.f, 0.f, 0.f, 0.f};
        #pragma unroll
        for (int ks = 0; ks < 8; ++ks) {
            uint4 uw = *(const uint4*)(wrow + 32 * ks);
            acc = __builtin_amdgcn_mfma_f32_16x16x32_bf16(
                aH[ks], __builtin_bit_cast(short8, uw), acc, 0, 0, 0);
        }
        float bv = b2o[ntg * 16 + ml];
        #pragma unroll
        for (int reg = 0; reg < 4; ++reg)
            h2L[q * 4 + reg][ntg * 16 + ml] = f2bf(fmaxf(acc[reg] + bv, 0.f));
    }
    __syncthreads();

    #pragma unroll
    for (int ks = 0; ks < 8; ++ks)
        aH[ks] = *(const short8*)&h2L[ml][32 * ks + q * 8];
    {
        const unsigned short* wrow = O3b + (size_t)(w * 16 + ml) * NH + q * 8;
        f32x4 acc = (f32x4){0.f, 0.f, 0.f, 0.f};
        #pragma unroll
        for (int ks = 0; ks < 8; ++ks) {
            uint4 uw = *(const uint4*)(wrow + 32 * ks);
            acc = __builtin_amdgcn_mfma_f32_16x16x32_bf16(
                aH[ks], __builtin_bit_cast(short8, uw), acc, 0, 0, 0);
        }
        float bv = b3o[w * 16 + ml];
        #pragma unroll
        for (int reg = 0; reg < 4; ++reg)
            out[(size_t)(row0 + q * 4 + reg) * NO + w * 16 + ml] = acc[reg] + bv;
    }
}

// ---------------------------------------------------------------------------
extern "C" void kernel_launch(void* const* d_in, const int* in_sizes, int n_in,
                              void* d_out, int out_size, void* d_ws, size_t ws_size,
                              hipStream_t stream) {
    const float* x   = (const float*)d_in[0];
    const float* rt  = (const float*)d_in[3];
    const float* W1  = (const float*)d_in[4];
    const float* b1  = (const float*)d_in[5];
    const float* W2  = (const float*)d_in[6];
    const float* b2  = (const float*)d_in[7];
    const float* O1  = (const float*)d_in[8];
    const float* b1o = (const float*)d_in[9];
    const float* O2  = (const float*)d_in[10];
    const float* b2o = (const float*)d_in[11];
    const float* O3  = (const float*)d_in[12];
    const float* b3o = (const float*)d_in[13];

    float* ws  = (float*)d_ws;
    unsigned short* psb = (unsigned short*)ws;
    unsigned short* prb = (unsigned short*)(ws + 524288);
    unsigned short* w2b = (unsigned short*)(ws + 1048576);
    float* agg = ws + 1056768;
    unsigned short* o1b = (unsigned short*)(ws + 1318912);
    unsigned short* o2b = (unsigned short*)(ws + 1327104);
    unsigned short* o3b = (unsigned short*)(ws + 1359872);
    float* out = (float*)d_out;

    hipLaunchKernelGGL(prep_kernel, dim3(704), dim3(256), 0, stream,
                       x, W1, b1, W2, O1, O2, O3, psb, prb, w2b, o1b, o2b, o3b);
    hipLaunchKernelGGL(edge_kernel, dim3(2048), dim3(256), 0, stream,
                       rt, b2, psb, prb, w2b, agg);
    hipLaunchKernelGGL(node_kernel, dim3(256), dim3(256), 0, stream,
                       agg, o1b, b1o, o2b, b2o, o3b, b3o, out);
}

// Round 7
// 130.575 us; speedup vs baseline: 1.0261x; 1.0261x over previous
//
#include <hip/hip_runtime.h>

#define BB 32
#define NN_ 128
#define NIN 64
#define MH 256
#define MO 64
#define NH 256
#define NO 64
#define EDGES 16256

typedef __attribute__((ext_vector_type(8))) short short8;   // 8 bf16 = 4 VGPRs
typedef __attribute__((ext_vector_type(4))) float f32x4;    // MFMA acc
typedef __attribute__((ext_vector_type(2))) float f32x2;    // v_pk_* pair

// ws layout (floats):
//   psb: [B][32][128][8] bf16  off 0        = 524288 floats
//   prb: [B][N][256]     bf16  off 524288   = 524288 floats
//   w2b: [32][64][8]     bf16  off 1048576  = 8192 floats
//   agg: [B][N][MO]      fp32  off 1056768  = 262144 floats
//   o1b: [256][64]       bf16  off 1318912  = 8192 floats
//   o2b: [256][256]      bf16  off 1327104  = 32768 floats
//   o3b: [64][256]       bf16  off 1359872  = 8192 floats

static __device__ __forceinline__ unsigned short f2bf(float f) {  // RNE-ish
    unsigned u = __float_as_uint(f);
    u = (u + 0x7fffu + ((u >> 16) & 1u)) >> 16;
    return (unsigned short)u;
}

// pack two fp32 into packed bf16 (round-half-away; valid for any sign)
static __device__ __forceinline__ unsigned bf_pack(float lo, float hi) {
    return __builtin_amdgcn_perm(__float_as_uint(hi) + 0x8000u,
                                 __float_as_uint(lo) + 0x8000u, 0x07060302u);
}

static __device__ __forceinline__ short8 pack8(float4 f0, float4 f1) {
    uint4 u;
    u.x = bf_pack(f0.x, f0.y);
    u.y = bf_pack(f0.z, f0.w);
    u.z = bf_pack(f1.x, f1.y);
    u.w = bf_pack(f1.z, f1.w);
    return __builtin_bit_cast(short8, u);
}

// unpack uint4 (8 packed bf16) into 4 f32x2 pairs
static __device__ __forceinline__ void unpack8v(uint4 u, f32x2* f) {
    f[0] = (f32x2){__uint_as_float(u.x << 16), __uint_as_float(u.x & 0xffff0000u)};
    f[1] = (f32x2){__uint_as_float(u.y << 16), __uint_as_float(u.y & 0xffff0000u)};
    f[2] = (f32x2){__uint_as_float(u.z << 16), __uint_as_float(u.z & 0xffff0000u)};
    f[3] = (f32x2){__uint_as_float(u.w << 16), __uint_as_float(u.w & 0xffff0000u)};
}

// A-fragment build: relu(s+p) with v_pk_add_f32 / v_pk_max_f32, pack w/ round
static __device__ __forceinline__ short8 buildAv(const f32x2* s, const f32x2* p) {
    uint4 u;
    #pragma unroll
    for (int i = 0; i < 4; ++i) {
        f32x2 h = s[i] + p[i];                                   // v_pk_add_f32
        h = __builtin_elementwise_max(h, (f32x2){0.f, 0.f});     // v_pk_max_f32
        ((unsigned*)&u)[i] = bf_pack(h.x, h.y);
    }
    return __builtin_bit_cast(short8, u);
}

// ---------------------------------------------------------------------------
// Kernel 1: prep (unchanged).
// ---------------------------------------------------------------------------
__global__ __launch_bounds__(256) void prep_kernel(
    const float* __restrict__ x, const float* __restrict__ W1,
    const float* __restrict__ b1, const float* __restrict__ W2,
    const float* __restrict__ O1, const float* __restrict__ O2,
    const float* __restrict__ O3,
    unsigned short* __restrict__ psb, unsigned short* __restrict__ prb,
    unsigned short* __restrict__ w2b, unsigned short* __restrict__ o1b,
    unsigned short* __restrict__ o2b, unsigned short* __restrict__ o3b)
{
    int blk = blockIdx.x;
    int t = threadIdx.x;
    if (blk < 256) {
        int row0 = blk << 4;
        int b = blk >> 3;
        int w = t >> 6, lane = t & 63, ml = lane & 15, q = lane >> 4;

        short8 aX[2];
        #pragma unroll
        for (int s = 0; s < 2; ++s) {
            const float* base = x + (size_t)(row0 + ml) * NIN + s * 32 + q * 8;
            aX[s] = pack8(*(const float4*)base, *(const float4*)(base + 4));
        }

        #pragma unroll
        for (int half = 0; half < 2; ++half) {
            #pragma unroll
            for (int nt = 0; nt < 4; ++nt) {
                int col = w * 64 + nt * 16 + ml;
                const float* wrow = W1 + (size_t)col * (2 * NIN) + half * 64 + q * 8;
                f32x4 acc = (f32x4){0.f, 0.f, 0.f, 0.f};
                #pragma unroll
                for (int s = 0; s < 2; ++s) {
                    short8 bw = pack8(*(const float4*)(wrow + 32 * s),
                                      *(const float4*)(wrow + 32 * s + 4));
                    acc = __builtin_amdgcn_mfma_f32_16x16x32_bf16(aX[s], bw, acc, 0, 0, 0);
                }
                if (half == 0) {
                    #pragma unroll
                    for (int reg = 0; reg < 4; ++reg) {
                        int n = (row0 + q * 4 + reg) & 127;
                        psb[((size_t)(b * 32 + (col >> 3)) * NN_ + n) * 8 + (col & 7)]
                            = f2bf(acc[reg]);
                    }
                } else {
                    float bv = b1[col];
                    #pragma unroll
                    for (int reg = 0; reg < 4; ++reg) {
                        int n = (row0 + q * 4 + reg) & 127;
                        prb[((size_t)(b * NN_) + n) * MH + col] = f2bf(acc[reg] + bv);
                    }
                }
            }
        }
    } else if (blk < 320) {
        int i = ((blk - 256) << 8) + t;
        int kc4 = i >> 9, rem = i & 511;
        int n = rem >> 3, k7 = i & 7;
        w2b[i] = f2bf(W2[n * MH + kc4 * 8 + k7]);
    } else {
        int i = ((blk - 320) << 8) + t;
        if (i < 16384)       o1b[i]         = f2bf(O1[i]);
        else if (i < 81920)  o2b[i - 16384] = f2bf(O2[i - 16384]);
        else                 o3b[i - 81920] = f2bf(O3[i - 81920]);
    }
}

// ---------------------------------------------------------------------------
// Kernel 2: edge fc2, bf16 MFMA, 2 receivers/block, dense sender mapping.
// R7: (a) XCD-affine block index: blk = pair*32 + b, so all 64 blocks of a
//     batch share blk%8 (same XCD) -> per-XCD hot set ~0.5 MB, no L2 thrash.
//     (b) rt loads are non-temporal (streaming; don't evict ps/pr).
//     (c) no explicit prefetch (R6 proved neutral), occupancy 4 blocks/CU.
// ---------------------------------------------------------------------------
__global__ __launch_bounds__(256, 4) void edge_kernel(
    const float* __restrict__ rt, const float* __restrict__ b2,
    const unsigned short* __restrict__ psb, const unsigned short* __restrict__ prb,
    const unsigned short* __restrict__ w2b, float* __restrict__ agg)
{
    int blk = blockIdx.x;
    int b = blk & 31;                  // batch in LOW bits: same-batch -> same XCD
    int r0 = (blk >> 5) << 1;
    int tid = threadIdx.x;
    int w = tid >> 6, lane = tid & 63, ml = lane & 15, q = lane >> 4;

    __shared__ float rtw_lds[2][128];
    __shared__ float red[2][4][64];
    {
        int rr = tid >> 7, s = tid & 127;
        int r = r0 + rr;
        float v = 0.f;
        if (s != r) {
            int e = r * 127 + s - (s > r ? 1 : 0);
            const float* p = rt + ((size_t)(b * EDGES + e)) * 2;
            v = __builtin_nontemporal_load(p) + __builtin_nontemporal_load(p + 1);
        }
        rtw_lds[rr][s] = v;
    }
    __syncthreads();

    int slot0 = 32 * w + ml;
    int slot1 = slot0 + 16;

    const uint4* ps4 = (const uint4*)psb + (size_t)b * (32 * NN_);       // [kc4][node]
    const uint4* pr4_0 = (const uint4*)(prb + ((size_t)(b * NN_ + r0)) * MH);
    const uint4* pr4_1 = (const uint4*)(prb + ((size_t)(b * NN_ + r0 + 1)) * MH);
    const uint4* w24 = (const uint4*)w2b;                                // [kc4][n]

    f32x4 acc[2][2][4];   // [receiver][m-tile][n-tile]
    #pragma unroll
    for (int rr = 0; rr < 2; ++rr)
        #pragma unroll
        for (int mt = 0; mt < 2; ++mt)
            #pragma unroll
            for (int nt = 0; nt < 4; ++nt)
                acc[rr][mt][nt] = (f32x4){0.f, 0.f, 0.f, 0.f};

    #pragma unroll
    for (int kc = 0; kc < 8; ++kc) {
        int kc4 = 4 * kc + q;
        uint4 us0 = ps4[kc4 * NN_ + slot0];
        uint4 us1 = ps4[kc4 * NN_ + slot1];
        uint4 up0 = pr4_0[kc4];
        uint4 up1 = pr4_1[kc4];

        f32x2 s0f[4], s1f[4], p0f[4], p1f[4];
        unpack8v(us0, s0f); unpack8v(us1, s1f);
        unpack8v(up0, p0f); unpack8v(up1, p1f);

        short8 a00 = buildAv(s0f, p0f);   // r0, m-tile 0
        short8 a01 = buildAv(s1f, p0f);   // r0, m-tile 1
        short8 a10 = buildAv(s0f, p1f);   // r1, m-tile 0
        short8 a11 = buildAv(s1f, p1f);   // r1, m-tile 1

        #pragma unroll
        for (int nt = 0; nt < 4; ++nt) {
            short8 bw = __builtin_bit_cast(short8, w24[kc4 * 64 + 16 * nt + ml]);
            acc[0][0][nt] = __builtin_amdgcn_mfma_f32_16x16x32_bf16(a00, bw, acc[0][0][nt], 0, 0, 0);
            acc[0][1][nt] = __builtin_amdgcn_mfma_f32_16x16x32_bf16(a01, bw, acc[0][1][nt], 0, 0, 0);
            acc[1][0][nt] = __builtin_amdgcn_mfma_f32_16x16x32_bf16(a10, bw, acc[1][0][nt], 0, 0, 0);
            acc[1][1][nt] = __builtin_amdgcn_mfma_f32_16x16x32_bf16(a11, bw, acc[1][1][nt], 0, 0, 0);
        }
    }

    float b2c[4];
    #pragma unroll
    for (int nt = 0; nt < 4; ++nt) b2c[nt] = b2[16 * nt + ml];

    #pragma unroll
    for (int rr = 0; rr < 2; ++rr) {
        float colsum[4] = {0.f, 0.f, 0.f, 0.f};
        #pragma unroll
        for (int mt = 0; mt < 2; ++mt) {
            int slotbase = 32 * w + 16 * mt + 4 * q;
            #pragma unroll
            for (int reg = 0; reg < 4; ++reg) {
                float rw = rtw_lds[rr][slotbase + reg];
                #pragma unroll
                for (int nt = 0; nt < 4; ++nt)
                    colsum[nt] += fmaxf(acc[rr][mt][nt][reg] + b2c[nt], 0.f) * rw;
            }
        }
        #pragma unroll
        for (int nt = 0; nt < 4; ++nt) {
            colsum[nt] += __shfl_xor(colsum[nt], 16);
            colsum[nt] += __shfl_xor(colsum[nt], 32);
        }
        if (lane < 16) {
            #pragma unroll
            for (int nt = 0; nt < 4; ++nt) red[rr][w][16 * nt + ml] = colsum[nt];
        }
    }
    __syncthreads();
    if (tid < 128) {
        int rr = tid >> 6, o = tid & 63;
        agg[((size_t)(b * NN_ + r0 + rr)) * MO + o] =
            red[rr][0][o] + red[rr][1][o] + red[rr][2][o] + red[rr][3][o];
    }
}

// ---------------------------------------------------------------------------
// Kernel 3: node MLP as 3 chained bf16 MFMAs (unchanged).
// ---------------------------------------------------------------------------
__global__ __launch_bounds__(256) void node_kernel(
    const float* __restrict__ agg,
    const unsigned short* __restrict__ O1b, const float* __restrict__ b1o,
    const unsigned short* __restrict__ O2b, const float* __restrict__ b2o,
    const unsigned short* __restrict__ O3b, const float* __restrict__ b3o,
    float* __restrict__ out)
{
    int tid = threadIdx.x;
    int w = tid >> 6, lane = tid & 63, ml = lane & 15, q = lane >> 4;
    int row0 = blockIdx.x << 4;

    __shared__ unsigned short h1L[16][264];
    __shared__ unsigned short h2L[16][264];

    short8 aA[2];
    #pragma unroll
    for (int s = 0; s < 2; ++s) {
        const float* base = agg + (size_t)(row0 + ml) * MO + 32 * s + q * 8;
        aA[s] = pack8(*(const float4*)base, *(const float4*)(base + 4));
    }

    #pragma unroll
    for (int nt = 0; nt < 4; ++nt) {
        int ntg = w * 4 + nt;
        f32x4 acc = (f32x4){0.f, 0.f, 0.f, 0.f};
        #pragma unroll
        for (int s = 0; s < 2; ++s) {
            uint4 uw = *(const uint4*)(O1b + (size_t)(ntg * 16 + ml) * 64 + 32 * s + q * 8);
            acc = __builtin_amdgcn_mfma_f32_16x16x32_bf16(
                aA[s], __builtin_bit_cast(short8, uw), acc, 0, 0, 0);
        }
        float bv = b1o[ntg * 16 + ml];
        #pragma unroll
        for (int reg = 0; reg < 4; ++reg)
            h1L[q * 4 + reg][ntg * 16 + ml] = f2bf(fmaxf(acc[reg] + bv, 0.f));
    }
    __syncthreads();

    short8 aH[8];
    #pragma unroll
    for (int ks = 0; ks < 8; ++ks)
        aH[ks] = *(const short8*)&h1L[ml][32 * ks + q * 8];
    #pragma unroll
    for (int nt = 0; nt < 4; ++nt) {
        int ntg = w * 4 + nt;
        const unsigned short* wrow = O2b + (size_t)(ntg * 16 + ml) * NH + q * 8;
        f32x4 acc = (f32x4){0.f, 0.f, 0.f, 0.f};
        #pragma unroll
        for (int ks = 0; ks < 8; ++ks) {
            uint4 uw = *(const uint4*)(wrow + 32 * ks);
            acc = __builtin_amdgcn_mfma_f32_16x16x32_bf16(
                aH[ks], __builtin_bit_cast(short8, uw), acc, 0, 0, 0);
        }
        float bv = b2o[ntg * 16 + ml];
        #pragma unroll
        for (int reg = 0; reg < 4; ++reg)
            h2L[q * 4 + reg][ntg * 16 + ml] = f2bf(fmaxf(acc[reg] + bv, 0.f));
    }
    __syncthreads();

    #pragma unroll
    for (int ks = 0; ks < 8; ++ks)
        aH[ks] = *(const short8*)&h2L[ml][32 * ks + q * 8];
    {
        const unsigned short* wrow = O3b + (size_t)(w * 16 + ml) * NH + q * 8;
        f32x4 acc = (f32x4){0.f, 0.f, 0.f, 0.f};
        #pragma unroll
        for (int ks = 0; ks < 8; ++ks) {
            uint4 uw = *(const uint4*)(wrow + 32 * ks);
            acc = __builtin_amdgcn_mfma_f32_16x16x32_bf16(
                aH[ks], __builtin_bit_cast(short8, uw), acc, 0, 0, 0);
        }
        float bv = b3o[w * 16 + ml];
        #pragma unroll
        for (int reg = 0; reg < 4; ++reg)
            out[(size_t)(row0 + q * 4 + reg) * NO + w * 16 + ml] = acc[reg] + bv;
    }
}

// ---------------------------------------------------------------------------
extern "C" void kernel_launch(void* const* d_in, const int* in_sizes, int n_in,
                              void* d_out, int out_size, void* d_ws, size_t ws_size,
                              hipStream_t stream) {
    const float* x   = (const float*)d_in[0];
    const float* rt  = (const float*)d_in[3];
    const float* W1  = (const float*)d_in[4];
    const float* b1  = (const float*)d_in[5];
    const float* W2  = (const float*)d_in[6];
    const float* b2  = (const float*)d_in[7];
    const float* O1  = (const float*)d_in[8];
    const float* b1o = (const float*)d_in[9];
    const float* O2  = (const float*)d_in[10];
    const float* b2o = (const float*)d_in[11];
    const float* O3  = (const float*)d_in[12];
    const float* b3o = (const float*)d_in[13];

    float* ws  = (float*)d_ws;
    unsigned short* psb = (unsigned short*)ws;
    unsigned short* prb = (unsigned short*)(ws + 524288);
    unsigned short* w2b = (unsigned short*)(ws + 1048576);
    float* agg = ws + 1056768;
    unsigned short* o1b = (unsigned short*)(ws + 1318912);
    unsigned short* o2b = (unsigned short*)(ws + 1327104);
    unsigned short* o3b = (unsigned short*)(ws + 1359872);
    float* out = (float*)d_out;

    hipLaunchKernelGGL(prep_kernel, dim3(704), dim3(256), 0, stream,
                       x, W1, b1, W2, O1, O2, O3, psb, prb, w2b, o1b, o2b, o3b);
    hipLaunchKernelGGL(edge_kernel, dim3(2048), dim3(256), 0, stream,
                       rt, b2, psb, prb, w2b, agg);
    hipLaunchKernelGGL(node_kernel, dim3(256), dim3(256), 0, stream,
                       agg, o1b, b1o, o2b, b2o, o3b, b3o, out);
}